// Round 10
// baseline (180.486 us; speedup 1.0000x reference)
//
#include <hip/hip_runtime.h>
#include <hip/hip_bf16.h>

using bf16 = __hip_bfloat16;

#define K 25
#define D0 7200
#define D1 3600
#define D2 1800

// pk stream word bases: [L0ch0][L0ch1][L1ch0][L1ch1][L2ch0][L2ch1], layout [k][d]
#define PKB_L1 360000
#define PKB_L2 540000
// pbias layout mirrors: bases 0/7200, 14400/18000, 21600/23400

#define NT 1024  // threads per fused block (16 waves/CU; LDS caps blocks/CU at 1)

__device__ __forceinline__ float b2f(ushort u) {
  unsigned int w = ((unsigned int)u) << 16;
  float f; __builtin_memcpy(&f, &w, 4); return f;
}
__device__ __forceinline__ ushort f2b(float f) {
  bf16 h = __float2bfloat16(f);
  ushort u; __builtin_memcpy(&u, &h, 2); return u;
}

// ---------------------------------------------------------------------------
// Prepack, segment-aligned: 104 blocks, each owns <=256 dims of ONE
// (layer, channel) segment. knn+weights staged into LDS with coalesced
// global reads; per-thread LDS reads are stride-25 (odd) -> bank-conflict
// free. Writes pk[k*dout+d] lane-coalesced. Also fp32 biases, y zero, flags.
// Dtype votes (validated r2-r9). fdt=1 -> floats bf16; idt=1 -> knn int64.
// Block counts per segment: L0: 29+29, L1: 15+15, L2: 8+8 = 104.
// ---------------------------------------------------------------------------
__global__ __launch_bounds__(256) void prepack_kernel(
    const void* __restrict__ x,
    const void* __restrict__ knn0, const void* __restrict__ knn1,
    const void* __restrict__ knn2,
    const void* __restrict__ wp0, const void* __restrict__ bp0,
    const void* __restrict__ wp1, const void* __restrict__ bp1,
    const void* __restrict__ wp2, const void* __restrict__ bp2,
    const void* __restrict__ wn0, const void* __restrict__ bn0,
    const void* __restrict__ wn1, const void* __restrict__ bn1,
    const void* __restrict__ wn2, const void* __restrict__ bn2,
    unsigned int* __restrict__ pk, float* __restrict__ pbias,
    float* __restrict__ y, int* __restrict__ flags) {
  __shared__ unsigned int s_idx[6400];   // 256 dims * 25
  __shared__ ushort s_w[6400];
  __shared__ int s_flags[2];
  const int t = threadIdx.x;

  if (t < 64) {
    const unsigned int u = ((const unsigned int*)x)[t * 997];
    const unsigned int e = (u >> 23) & 0xFF;
    const unsigned long long m = __ballot((e >= 192) || (e <= 30));
    if (t == 0) s_flags[0] = (__popcll(m) >= 32) ? 1 : 0;
  } else if (t < 128) {
    const int l = t - 64;
    const unsigned int hi = ((const unsigned int*)knn0)[2 * l + 1];
    const unsigned long long m = __ballot(hi != 0);
    if (l == 0) s_flags[1] = (m == 0ULL) ? 1 : 0;
  }
  __syncthreads();
  const int fdt = s_flags[0], idt = s_flags[1];

  if (blockIdx.x == 0 && t == 0) {
    flags[0] = fdt; flags[1] = idt; flags[16] = 0;
  }
  if (blockIdx.x < 4) y[blockIdx.x * 256 + t] = 0.0f;

  // segment mapping
  int bb = (int)blockIdx.x, dout, pkb, pbase, d0;
  const void *kn, *wsel, *bsel;
  if (bb < 58) {
    const int ch = bb >= 29; const int lb = ch ? bb - 29 : bb;
    dout = D0; kn = knn0; pkb = ch ? 180000 : 0; pbase = ch ? 7200 : 0;
    wsel = ch ? wn0 : wp0; bsel = ch ? bn0 : bp0; d0 = lb * 256;
  } else if (bb < 88) {
    bb -= 58; const int ch = bb >= 15; const int lb = ch ? bb - 15 : bb;
    dout = D1; kn = knn1; pkb = PKB_L1 + ch * 90000; pbase = 14400 + ch * D1;
    wsel = ch ? wn1 : wp1; bsel = ch ? bn1 : bp1; d0 = lb * 256;
  } else {
    bb -= 88; const int ch = bb >= 8; const int lb = ch ? bb - 8 : bb;
    dout = D2; kn = knn2; pkb = PKB_L2 + ch * 45000; pbase = 21600 + ch * D2;
    wsel = ch ? wn2 : wp2; bsel = ch ? bn2 : bp2; d0 = lb * 256;
  }
  const int cnt = min(256, dout - d0);
  const int n = cnt * K;

  if (idt) {
    const uint2* src = (const uint2*)kn + (size_t)d0 * K;
    for (int i = t; i < n; i += 256) s_idx[i] = src[i].x;
  } else {
    const unsigned int* src = (const unsigned int*)kn + (size_t)d0 * K;
    for (int i = t; i < n; i += 256) s_idx[i] = src[i];
  }
  if (fdt) {
    const ushort* src = (const ushort*)wsel + (size_t)d0 * K;
    for (int i = t; i < n; i += 256) s_w[i] = src[i];
  } else {
    const float* src = (const float*)wsel + (size_t)d0 * K;
    for (int i = t; i < n; i += 256) s_w[i] = f2b(src[i]);
  }
  __syncthreads();

  if (t < cnt) {
    const int d = d0 + t;
#pragma unroll
    for (int k = 0; k < K; ++k) {
      pk[pkb + k * dout + d] = (s_idx[t * K + k] << 16) | (unsigned int)s_w[t * K + k];
    }
    pbias[pbase + d] = fdt ? b2f(((const ushort*)bsel)[d]) : ((const float*)bsel)[d];
  }
}

// ---------------------------------------------------------------------------
// One LCN layer inside LDS. 2-way dim interleave: each thread runs dims
// d and d+NT with interleaved K-chains (2 independent pk-load->ds_read->fma
// streams per thread) to double memory-level parallelism.
// lds holds activations as [f][2] bf16 pairs (one uint per feature).
// ---------------------------------------------------------------------------
__device__ __forceinline__ void layer_run(ushort* lds, const unsigned int* __restrict__ pk,
                                          const float* __restrict__ pbias,
                                          int offIn, int offOut, int pkb, int pbb,
                                          int dout) {
  int d = threadIdx.x;
  for (; d + NT < dout; d += 2 * NT) {
    const unsigned int* s0 = pk + pkb + d;
    const unsigned int* s1 = s0 + NT;
    float a0 = 0.f, a1 = 0.f, c0 = 0.f, c1 = 0.f;
#pragma unroll
    for (int k = 0; k < K; ++k) {
      const unsigned int pw0 = s0[k * dout];
      const unsigned int pw1 = s1[k * dout];
      const unsigned int vv0 = *(const unsigned int*)&lds[offIn + ((pw0 >> 16) << 1)];
      const unsigned int vv1 = *(const unsigned int*)&lds[offIn + ((pw1 >> 16) << 1)];
      const float w0 = b2f((ushort)(pw0 & 0xFFFFu));
      const float w1 = b2f((ushort)(pw1 & 0xFFFFu));
      a0 = fmaf(w0, b2f((ushort)(vv0 & 0xFFFFu)), a0);
      a1 = fmaf(w0, b2f((ushort)(vv0 >> 16)), a1);
      c0 = fmaf(w1, b2f((ushort)(vv1 & 0xFFFFu)), c0);
      c1 = fmaf(w1, b2f((ushort)(vv1 >> 16)), c1);
    }
    const float bias0 = pbias[pbb + d];
    const float bias1 = pbias[pbb + d + NT];
    a0 = fmaxf(a0 + bias0, 0.f); a1 = fmaxf(a1 + bias0, 0.f);
    c0 = fmaxf(c0 + bias1, 0.f); c1 = fmaxf(c1 + bias1, 0.f);
    *(unsigned int*)&lds[offOut + (d << 1)] =
        (unsigned int)f2b(a0) | ((unsigned int)f2b(a1) << 16);
    *(unsigned int*)&lds[offOut + ((d + NT) << 1)] =
        (unsigned int)f2b(c0) | ((unsigned int)f2b(c1) << 16);
  }
  if (d < dout) {
    const unsigned int* s = pk + pkb + d;
    float a0 = 0.f, a1 = 0.f;
#pragma unroll
    for (int k = 0; k < K; ++k) {
      const unsigned int pw = s[k * dout];
      const unsigned int vv = *(const unsigned int*)&lds[offIn + ((pw >> 16) << 1)];
      const float w = b2f((ushort)(pw & 0xFFFFu));
      a0 = fmaf(w, b2f((ushort)(vv & 0xFFFFu)), a0);
      a1 = fmaf(w, b2f((ushort)(vv >> 16)), a1);
    }
    const float bias = pbias[pbb + d];
    a0 = fmaxf(a0 + bias, 0.f);
    a1 = fmaxf(a1 + bias, 0.f);
    *(unsigned int*)&lds[offOut + (d << 1)] =
        (unsigned int)f2b(a0) | ((unsigned int)f2b(a1) << 16);
  }
}

// ---------------------------------------------------------------------------
// Fused network: block = (channel, batch-slice of 2), NT=1024 (16 waves/CU).
// LDS plan (ushort idx): L0: in@0(28800) -> h0@28800(14400);
// L1: h0@28800 -> h1@0(7200); L2: h1@0 -> h2@7200(3600); fc reads h2@7200.
// ---------------------------------------------------------------------------
__global__ __launch_bounds__(NT) void lcn_fused(
    const void* __restrict__ x, const unsigned int* __restrict__ pk,
    const float* __restrict__ pbias,
    const void* __restrict__ fcpw, const void* __restrict__ fcnw,
    const void* __restrict__ fcpb, const void* __restrict__ fcnb,
    const void* __restrict__ f3w, const void* __restrict__ f3b,
    float* __restrict__ y, int* __restrict__ flags, void* __restrict__ out) {
  __shared__ ushort lds[43200];      // 86,400 B
  __shared__ float red[NT / 64][4];
  __shared__ int sflag;
  const int t = threadIdx.x;
  const int ch = blockIdx.x & 1;
  const int b0 = (blockIdx.x >> 1) * 2;

  if (t == 0) sflag = flags[0];
  __syncthreads();
  const int fdt = sflag;

  // ---- stage input rows b0, b0+1 (this channel's 14400 features) ----
  if (fdt) {
    const ushort* r0 = (const ushort*)x + (size_t)b0 * 28800 + ch * 14400;
    const ushort* r1 = r0 + 28800;
    for (int c = t; c < 3600; c += NT) {
      const ushort4 a = ((const ushort4*)r0)[c];
      const ushort4 b = ((const ushort4*)r1)[c];
      unsigned int* dst = (unsigned int*)&lds[c * 8];
      dst[0] = (unsigned int)a.x | ((unsigned int)b.x << 16);
      dst[1] = (unsigned int)a.y | ((unsigned int)b.y << 16);
      dst[2] = (unsigned int)a.z | ((unsigned int)b.z << 16);
      dst[3] = (unsigned int)a.w | ((unsigned int)b.w << 16);
    }
  } else {
    const float* r0 = (const float*)x + (size_t)b0 * 28800 + ch * 14400;
    const float* r1 = r0 + 28800;
    for (int c = t; c < 3600; c += NT) {
      const float4 a = ((const float4*)r0)[c];
      const float4 b = ((const float4*)r1)[c];
      unsigned int* dst = (unsigned int*)&lds[c * 8];
      dst[0] = (unsigned int)f2b(a.x) | ((unsigned int)f2b(b.x) << 16);
      dst[1] = (unsigned int)f2b(a.y) | ((unsigned int)f2b(b.y) << 16);
      dst[2] = (unsigned int)f2b(a.z) | ((unsigned int)f2b(b.z) << 16);
      dst[3] = (unsigned int)f2b(a.w) | ((unsigned int)f2b(b.w) << 16);
    }
  }
  __syncthreads();

  layer_run(lds, pk, pbias, 0, 28800, 0 + ch * 180000, 0 + ch * D0, D0);
  __syncthreads();
  layer_run(lds, pk, pbias, 28800, 0, PKB_L1 + ch * 90000, 14400 + ch * D1, D1);
  __syncthreads();
  layer_run(lds, pk, pbias, 0, 7200, PKB_L2 + ch * 45000, 21600 + ch * D2, D2);
  __syncthreads();

  // ---- fc: y[ch][o][b0..b0+1] = sum_d fw[o][d] * h2[d][.] ----
  {
    const void* fw = ch ? fcnw : fcpw;
    float a00 = 0.f, a01 = 0.f, a10 = 0.f, a11 = 0.f;
    for (int d = t; d < D2; d += NT) {
      const unsigned int vv = *(const unsigned int*)&lds[7200 + (d << 1)];
      const float v0 = b2f((ushort)(vv & 0xFFFFu));
      const float v1 = b2f((ushort)(vv >> 16));
      const float w0 = fdt ? b2f(((const ushort*)fw)[d]) : ((const float*)fw)[d];
      const float w1 = fdt ? b2f(((const ushort*)fw)[D2 + d]) : ((const float*)fw)[D2 + d];
      a00 = fmaf(w0, v0, a00); a01 = fmaf(w0, v1, a01);
      a10 = fmaf(w1, v0, a10); a11 = fmaf(w1, v1, a11);
    }
#pragma unroll
    for (int off = 32; off > 0; off >>= 1) {
      a00 += __shfl_down(a00, off);
      a01 += __shfl_down(a01, off);
      a10 += __shfl_down(a10, off);
      a11 += __shfl_down(a11, off);
    }
    const int wave = t >> 6, lane = t & 63;
    if (lane == 0) {
      red[wave][0] = a00; red[wave][1] = a01; red[wave][2] = a10; red[wave][3] = a11;
    }
    __syncthreads();
    if (t == 0) {
      float s00 = 0.f, s01 = 0.f, s10 = 0.f, s11 = 0.f;
#pragma unroll
      for (int wv = 0; wv < NT / 64; ++wv) {
        s00 += red[wv][0]; s01 += red[wv][1]; s10 += red[wv][2]; s11 += red[wv][3];
      }
      atomicAdd(&y[(ch * 2 + 0) * 256 + b0], s00);
      atomicAdd(&y[(ch * 2 + 0) * 256 + b0 + 1], s01);
      atomicAdd(&y[(ch * 2 + 1) * 256 + b0], s10);
      atomicAdd(&y[(ch * 2 + 1) * 256 + b0 + 1], s11);
    }
  }

  // ---- last-done block computes the final combine (round-5-validated) ----
  __syncthreads();
  if (t == 0) {
    __threadfence();
    sflag = (atomicAdd(&flags[16], 1) == (int)gridDim.x - 1) ? 1 : 0;
  }
  __syncthreads();
  if (sflag && t < 256) {
    const int b = t;
    const float y0 = atomicAdd(&y[0 * 256 + b], 0.0f);
    const float y1 = atomicAdd(&y[1 * 256 + b], 0.0f);
    const float y2 = atomicAdd(&y[2 * 256 + b], 0.0f);
    const float y3 = atomicAdd(&y[3 * 256 + b], 0.0f);
    const float bp0v = fdt ? b2f(((const ushort*)fcpb)[0]) : ((const float*)fcpb)[0];
    const float bp1v = fdt ? b2f(((const ushort*)fcpb)[1]) : ((const float*)fcpb)[1];
    const float bn0v = fdt ? b2f(((const ushort*)fcnb)[0]) : ((const float*)fcnb)[0];
    const float bn1v = fdt ? b2f(((const ushort*)fcnb)[1]) : ((const float*)fcnb)[1];
    const float h0v = fmaxf(y0 + bp0v, 0.f);
    const float h1v = fmaxf(y1 + bp1v, 0.f);
    const float h2v = fmaxf(y2 + bn0v, 0.f);
    const float h3v = fmaxf(y3 + bn1v, 0.f);
#pragma unroll
    for (int o = 0; o < 2; ++o) {
      float w0, w1, w2, w3, bb;
      if (fdt) {
        const ushort* fp = (const ushort*)f3w;
        w0 = b2f(fp[o * 4 + 0]); w1 = b2f(fp[o * 4 + 1]);
        w2 = b2f(fp[o * 4 + 2]); w3 = b2f(fp[o * 4 + 3]);
        bb = b2f(((const ushort*)f3b)[o]);
      } else {
        const float* fp = (const float*)f3w;
        w0 = fp[o * 4 + 0]; w1 = fp[o * 4 + 1];
        w2 = fp[o * 4 + 2]; w3 = fp[o * 4 + 3];
        bb = ((const float*)f3b)[o];
      }
      float r = bb;
      r = fmaf(w0, h0v, r); r = fmaf(w1, h1v, r);
      r = fmaf(w2, h2v, r); r = fmaf(w3, h3v, r);
      if (fdt) ((ushort*)out)[b * 2 + o] = f2b(r);
      else     ((float*)out)[b * 2 + o] = r;
    }
  }
}

extern "C" void kernel_launch(void* const* d_in, const int* in_sizes, int n_in,
                              void* d_out, int out_size, void* d_ws, size_t ws_size,
                              hipStream_t stream) {
  const void* x    = d_in[0];
  const void* knn0 = d_in[1];
  const void* knn1 = d_in[2];
  const void* knn2 = d_in[3];
  const void* wp0  = d_in[4];  const void* bp0 = d_in[5];
  const void* wp1  = d_in[6];  const void* bp1 = d_in[7];
  const void* wp2  = d_in[8];  const void* bp2 = d_in[9];
  const void* fcpw = d_in[10]; const void* fcpb = d_in[11];
  const void* wn0  = d_in[12]; const void* bn0 = d_in[13];
  const void* wn1  = d_in[14]; const void* bn1 = d_in[15];
  const void* wn2  = d_in[16]; const void* bn2 = d_in[17];
  const void* fcnw = d_in[18]; const void* fcnb = d_in[19];
  const void* f3w  = d_in[20]; const void* f3b  = d_in[21];

  char* ws = (char*)d_ws;
  unsigned int* pk = (unsigned int*)(ws);         // 630000*4 = 2,520,000 B
  float* pbias = (float*)(ws + 2520000);          // 25200*4  =   100,800 B
  float* y     = (float*)(ws + 2620800);          // 1024*4   =     4,096 B
  int* flags   = (int*)(ws + 2624896);            // flags[0..1], flags[16]

  prepack_kernel<<<104, 256, 0, stream>>>(x, knn0, knn1, knn2,
                                          wp0, bp0, wp1, bp1, wp2, bp2,
                                          wn0, bn0, wn1, bn1, wn2, bn2,
                                          pk, pbias, y, flags);

  lcn_fused<<<256, NT, 0, stream>>>(x, pk, pbias, fcpw, fcnw, fcpb, fcnb,
                                    f3w, f3b, y, flags, d_out);
}

// Round 11
// 147.981 us; speedup vs baseline: 1.2197x; 1.2197x over previous
//
#include <hip/hip_runtime.h>
#include <hip/hip_bf16.h>

using bf16 = __hip_bfloat16;

#define K 25
#define D0 7200
#define D1 3600
#define D2 1800

// pk stream word bases: [L0ch0][L0ch1][L1ch0][L1ch1][L2ch0][L2ch1], layout [k][d]
#define PKB_L1 360000
#define PKB_L2 540000
// pbias layout: [L0ch0][L0ch1][L1ch0][L1ch1][L2ch0][L2ch1] (25200 entries)
#define NPB    25200

#define NT 1024  // threads per fused block (16 waves/CU; LDS caps blocks/CU at 1)

__device__ __forceinline__ float b2f(ushort u) {
  unsigned int w = ((unsigned int)u) << 16;
  float f; __builtin_memcpy(&f, &w, 4); return f;
}
__device__ __forceinline__ ushort f2b(float f) {
  bf16 h = __float2bfloat16(f);
  ushort u; __builtin_memcpy(&u, &h, 2); return u;
}

// ---------------------------------------------------------------------------
// Prepack, one thread per output dim (25200 dims): reads 25 contiguous
// idx/w entries, writes pk[k*dout+d] lane-coalesced. Also fp32 biases,
// y zeroing, flags. Dtype votes (validated r2-r9) per block.
// fdt=1 -> floats are bf16; idt=1 -> knn is int64.
// ---------------------------------------------------------------------------
__global__ __launch_bounds__(256) void prepack_kernel(
    const void* __restrict__ x,
    const void* __restrict__ knn0, const void* __restrict__ knn1,
    const void* __restrict__ knn2,
    const void* __restrict__ wp0, const void* __restrict__ bp0,
    const void* __restrict__ wp1, const void* __restrict__ bp1,
    const void* __restrict__ wp2, const void* __restrict__ bp2,
    const void* __restrict__ wn0, const void* __restrict__ bn0,
    const void* __restrict__ wn1, const void* __restrict__ bn1,
    const void* __restrict__ wn2, const void* __restrict__ bn2,
    unsigned int* __restrict__ pk, float* __restrict__ pbias,
    float* __restrict__ y, int* __restrict__ flags) {
  __shared__ int s_flags[2];
  const int t = threadIdx.x;
  if (t < 64) {
    const unsigned int u = ((const unsigned int*)x)[t * 997];
    const unsigned int e = (u >> 23) & 0xFF;
    const unsigned long long m = __ballot((e >= 192) || (e <= 30));
    if (t == 0) s_flags[0] = (__popcll(m) >= 32) ? 1 : 0;
  } else if (t < 128) {
    const int l = t - 64;
    const unsigned int hi = ((const unsigned int*)knn0)[2 * l + 1];
    const unsigned long long m = __ballot(hi != 0);
    if (l == 0) s_flags[1] = (m == 0ULL) ? 1 : 0;
  }
  __syncthreads();
  const int fdt = s_flags[0], idt = s_flags[1];

  if (blockIdx.x == 0 && t == 0) {
    flags[0] = fdt; flags[1] = idt; flags[16] = 0;
  }

  const int gid = blockIdx.x * 256 + t;
  if (gid < NPB) {
    // map gid -> (layer, ch, d)
    int i = gid, d, dout, pkb;
    const void *kn, *wsel, *bsel;
    if (i < 14400) {
      const int ch = i / D0; d = i - ch * D0; dout = D0;
      pkb = ch * 180000; kn = knn0;
      wsel = ch ? wn0 : wp0; bsel = ch ? bn0 : bp0;
    } else if (i < 21600) {
      i -= 14400; const int ch = i / D1; d = i - ch * D1; dout = D1;
      pkb = PKB_L1 + ch * 90000; kn = knn1;
      wsel = ch ? wn1 : wp1; bsel = ch ? bn1 : bp1;
    } else {
      i -= 21600; const int ch = i / D2; d = i - ch * D2; dout = D2;
      pkb = PKB_L2 + ch * 45000; kn = knn2;
      wsel = ch ? wn2 : wp2; bsel = ch ? bn2 : bp2;
    }
    const int pos0 = d * K;
#pragma unroll
    for (int k = 0; k < K; ++k) {
      const unsigned int idx = idt ? ((const unsigned int*)kn)[2 * (pos0 + k)]
                                   : ((const unsigned int*)kn)[pos0 + k];
      const ushort wb = fdt ? ((const ushort*)wsel)[pos0 + k]
                            : f2b(((const float*)wsel)[pos0 + k]);
      pk[pkb + k * dout + d] = (idx << 16) | (unsigned int)wb;
    }
    pbias[gid] = fdt ? b2f(((const ushort*)bsel)[d]) : ((const float*)bsel)[d];
  } else if (gid < NPB + 1024) {
    y[gid - NPB] = 0.0f;
  }
}

// ---------------------------------------------------------------------------
// One LCN layer inside LDS: out[d][0..1] = relu(sum_k w * in[idx][0..1] + b)
// lds holds activations as [f][2] bf16 pairs (one uint per feature).
// pk layout [k][d]: lanes (consecutive d) load coalesced per k.
// r11: even/odd accumulator split (chain depth 25 -> 13); otherwise the
// r9 form — do NOT interleave dims (r10: VGPR crunch de-pipelines loads).
// ---------------------------------------------------------------------------
__device__ __forceinline__ void layer_run(ushort* lds, const unsigned int* __restrict__ pk,
                                          const float* __restrict__ pbias,
                                          int offIn, int offOut, int pkb, int pbb,
                                          int dout) {
  for (int d = threadIdx.x; d < dout; d += NT) {
    const unsigned int* s = pk + pkb + d;
    float a0e = 0.f, a0o = 0.f, a1e = 0.f, a1o = 0.f;
#pragma unroll
    for (int k = 0; k < K; ++k) {
      const unsigned int pw = s[k * dout];
      const unsigned int vv = *(const unsigned int*)&lds[offIn + ((pw >> 16) << 1)];
      const float w = b2f((ushort)(pw & 0xFFFFu));
      const float v0 = b2f((ushort)(vv & 0xFFFFu));
      const float v1 = b2f((ushort)(vv >> 16));
      if (k & 1) {
        a0o = fmaf(w, v0, a0o);
        a1o = fmaf(w, v1, a1o);
      } else {
        a0e = fmaf(w, v0, a0e);
        a1e = fmaf(w, v1, a1e);
      }
    }
    const float bias = pbias[pbb + d];
    const float a0 = fmaxf(a0e + a0o + bias, 0.f);
    const float a1 = fmaxf(a1e + a1o + bias, 0.f);
    *(unsigned int*)&lds[offOut + (d << 1)] =
        (unsigned int)f2b(a0) | ((unsigned int)f2b(a1) << 16);
  }
}

// ---------------------------------------------------------------------------
// Fused network: block = (channel, batch-slice of 2), NT=1024 (16 waves/CU)
// to hide LDS gather latency (LDS 86.4 KB -> 1 block/CU regardless).
// LDS plan (ushort idx): L0: in@0(28800) -> h0@28800(14400);
// L1: h0@28800 -> h1@0(7200); L2: h1@0 -> h2@7200(3600); fc reads h2@7200.
// ---------------------------------------------------------------------------
__global__ __launch_bounds__(NT) void lcn_fused(
    const void* __restrict__ x, const unsigned int* __restrict__ pk,
    const float* __restrict__ pbias,
    const void* __restrict__ fcpw, const void* __restrict__ fcnw,
    const void* __restrict__ fcpb, const void* __restrict__ fcnb,
    const void* __restrict__ f3w, const void* __restrict__ f3b,
    float* __restrict__ y, int* __restrict__ flags, void* __restrict__ out) {
  __shared__ ushort lds[43200];      // 86,400 B
  __shared__ float red[NT / 64][4];
  __shared__ int sflag;
  const int t = threadIdx.x;
  const int ch = blockIdx.x & 1;
  const int b0 = (blockIdx.x >> 1) * 2;

  if (t == 0) sflag = flags[0];
  __syncthreads();
  const int fdt = sflag;

  // ---- stage input rows b0, b0+1 (this channel's 14400 features) ----
  if (fdt) {
    const ushort* r0 = (const ushort*)x + (size_t)b0 * 28800 + ch * 14400;
    const ushort* r1 = r0 + 28800;
    for (int c = t; c < 3600; c += NT) {
      const ushort4 a = ((const ushort4*)r0)[c];
      const ushort4 b = ((const ushort4*)r1)[c];
      unsigned int* dst = (unsigned int*)&lds[c * 8];
      dst[0] = (unsigned int)a.x | ((unsigned int)b.x << 16);
      dst[1] = (unsigned int)a.y | ((unsigned int)b.y << 16);
      dst[2] = (unsigned int)a.z | ((unsigned int)b.z << 16);
      dst[3] = (unsigned int)a.w | ((unsigned int)b.w << 16);
    }
  } else {
    const float* r0 = (const float*)x + (size_t)b0 * 28800 + ch * 14400;
    const float* r1 = r0 + 28800;
    for (int c = t; c < 3600; c += NT) {
      const float4 a = ((const float4*)r0)[c];
      const float4 b = ((const float4*)r1)[c];
      unsigned int* dst = (unsigned int*)&lds[c * 8];
      dst[0] = (unsigned int)f2b(a.x) | ((unsigned int)f2b(b.x) << 16);
      dst[1] = (unsigned int)f2b(a.y) | ((unsigned int)f2b(b.y) << 16);
      dst[2] = (unsigned int)f2b(a.z) | ((unsigned int)f2b(b.z) << 16);
      dst[3] = (unsigned int)f2b(a.w) | ((unsigned int)f2b(b.w) << 16);
    }
  }
  __syncthreads();

  layer_run(lds, pk, pbias, 0, 28800, 0 + ch * 180000, 0 + ch * D0, D0);
  __syncthreads();
  layer_run(lds, pk, pbias, 28800, 0, PKB_L1 + ch * 90000, 14400 + ch * D1, D1);
  __syncthreads();
  layer_run(lds, pk, pbias, 0, 7200, PKB_L2 + ch * 45000, 21600 + ch * D2, D2);
  __syncthreads();

  // ---- fc: y[ch][o][b0..b0+1] = sum_d fw[o][d] * h2[d][.] ----
  {
    const void* fw = ch ? fcnw : fcpw;
    float a00 = 0.f, a01 = 0.f, a10 = 0.f, a11 = 0.f;
    for (int d = t; d < D2; d += NT) {
      const unsigned int vv = *(const unsigned int*)&lds[7200 + (d << 1)];
      const float v0 = b2f((ushort)(vv & 0xFFFFu));
      const float v1 = b2f((ushort)(vv >> 16));
      const float w0 = fdt ? b2f(((const ushort*)fw)[d]) : ((const float*)fw)[d];
      const float w1 = fdt ? b2f(((const ushort*)fw)[D2 + d]) : ((const float*)fw)[D2 + d];
      a00 = fmaf(w0, v0, a00); a01 = fmaf(w0, v1, a01);
      a10 = fmaf(w1, v0, a10); a11 = fmaf(w1, v1, a11);
    }
#pragma unroll
    for (int off = 32; off > 0; off >>= 1) {
      a00 += __shfl_down(a00, off);
      a01 += __shfl_down(a01, off);
      a10 += __shfl_down(a10, off);
      a11 += __shfl_down(a11, off);
    }
    const int wave = t >> 6, lane = t & 63;
    if (lane == 0) {
      red[wave][0] = a00; red[wave][1] = a01; red[wave][2] = a10; red[wave][3] = a11;
    }
    __syncthreads();
    if (t == 0) {
      float s00 = 0.f, s01 = 0.f, s10 = 0.f, s11 = 0.f;
#pragma unroll
      for (int wv = 0; wv < NT / 64; ++wv) {
        s00 += red[wv][0]; s01 += red[wv][1]; s10 += red[wv][2]; s11 += red[wv][3];
      }
      atomicAdd(&y[(ch * 2 + 0) * 256 + b0], s00);
      atomicAdd(&y[(ch * 2 + 0) * 256 + b0 + 1], s01);
      atomicAdd(&y[(ch * 2 + 1) * 256 + b0], s10);
      atomicAdd(&y[(ch * 2 + 1) * 256 + b0 + 1], s11);
    }
  }

  // ---- last-done block computes the final combine (round-5-validated) ----
  __syncthreads();
  if (t == 0) {
    __threadfence();
    sflag = (atomicAdd(&flags[16], 1) == (int)gridDim.x - 1) ? 1 : 0;
  }
  __syncthreads();
  if (sflag && t < 256) {
    const int b = t;
    const float y0 = atomicAdd(&y[0 * 256 + b], 0.0f);
    const float y1 = atomicAdd(&y[1 * 256 + b], 0.0f);
    const float y2 = atomicAdd(&y[2 * 256 + b], 0.0f);
    const float y3 = atomicAdd(&y[3 * 256 + b], 0.0f);
    const float bp0v = fdt ? b2f(((const ushort*)fcpb)[0]) : ((const float*)fcpb)[0];
    const float bp1v = fdt ? b2f(((const ushort*)fcpb)[1]) : ((const float*)fcpb)[1];
    const float bn0v = fdt ? b2f(((const ushort*)fcnb)[0]) : ((const float*)fcnb)[0];
    const float bn1v = fdt ? b2f(((const ushort*)fcnb)[1]) : ((const float*)fcnb)[1];
    const float h0v = fmaxf(y0 + bp0v, 0.f);
    const float h1v = fmaxf(y1 + bp1v, 0.f);
    const float h2v = fmaxf(y2 + bn0v, 0.f);
    const float h3v = fmaxf(y3 + bn1v, 0.f);
#pragma unroll
    for (int o = 0; o < 2; ++o) {
      float w0, w1, w2, w3, bb;
      if (fdt) {
        const ushort* fp = (const ushort*)f3w;
        w0 = b2f(fp[o * 4 + 0]); w1 = b2f(fp[o * 4 + 1]);
        w2 = b2f(fp[o * 4 + 2]); w3 = b2f(fp[o * 4 + 3]);
        bb = b2f(((const ushort*)f3b)[o]);
      } else {
        const float* fp = (const float*)f3w;
        w0 = fp[o * 4 + 0]; w1 = fp[o * 4 + 1];
        w2 = fp[o * 4 + 2]; w3 = fp[o * 4 + 3];
        bb = ((const float*)f3b)[o];
      }
      float r = bb;
      r = fmaf(w0, h0v, r); r = fmaf(w1, h1v, r);
      r = fmaf(w2, h2v, r); r = fmaf(w3, h3v, r);
      if (fdt) ((ushort*)out)[b * 2 + o] = f2b(r);
      else     ((float*)out)[b * 2 + o] = r;
    }
  }
}

extern "C" void kernel_launch(void* const* d_in, const int* in_sizes, int n_in,
                              void* d_out, int out_size, void* d_ws, size_t ws_size,
                              hipStream_t stream) {
  const void* x    = d_in[0];
  const void* knn0 = d_in[1];
  const void* knn1 = d_in[2];
  const void* knn2 = d_in[3];
  const void* wp0  = d_in[4];  const void* bp0 = d_in[5];
  const void* wp1  = d_in[6];  const void* bp1 = d_in[7];
  const void* wp2  = d_in[8];  const void* bp2 = d_in[9];
  const void* fcpw = d_in[10]; const void* fcpb = d_in[11];
  const void* wn0  = d_in[12]; const void* bn0 = d_in[13];
  const void* wn1  = d_in[14]; const void* bn1 = d_in[15];
  const void* wn2  = d_in[16]; const void* bn2 = d_in[17];
  const void* fcnw = d_in[18]; const void* fcnb = d_in[19];
  const void* f3w  = d_in[20]; const void* f3b  = d_in[21];

  char* ws = (char*)d_ws;
  unsigned int* pk = (unsigned int*)(ws);         // 630000*4 = 2,520,000 B
  float* pbias = (float*)(ws + 2520000);          // 25200*4  =   100,800 B
  float* y     = (float*)(ws + 2620800);          // 1024*4   =     4,096 B
  int* flags   = (int*)(ws + 2624896);            // flags[0..1], flags[16]

  // tasks: 25200 dims + 1024 y-zero = 26224 -> 103 blocks of 256
  prepack_kernel<<<103, 256, 0, stream>>>(x, knn0, knn1, knn2,
                                          wp0, bp0, wp1, bp1, wp2, bp2,
                                          wn0, bn0, wn1, bn1, wn2, bn2,
                                          pk, pbias, y, flags);

  lcn_fused<<<256, NT, 0, stream>>>(x, pk, pbias, fcpw, fcnw, fcpb, fcnb,
                                    f3w, f3b, y, flags, d_out);
}